// Round 1
// baseline (1330.467 us; speedup 1.0000x reference)
//
#include <hip/hip_runtime.h>
#include <hip/hip_bf16.h>

#define N_ATOMS 20000
#define N_EDGES 500000
#define FDIM    128
#define TFDIM   384

__device__ inline float4 ld4(const float* p) { return *(const float4*)p; }
__device__ inline void st4(float* p, float4 v) { *(float4*)p = v; }
__device__ inline float4 mul4(float4 a, float4 b) {
    return make_float4(a.x*b.x, a.y*b.y, a.z*b.z, a.w*b.w);
}
__device__ inline void fma4(float4& acc, float4 a, float4 b) {
    acc.x += a.x*b.x; acc.y += a.y*b.y; acc.z += a.z*b.z; acc.w += a.w*b.w;
}
__device__ inline void fma4s(float4& acc, float4 a, float s) {
    acc.x += a.x*s; acc.y += a.y*s; acc.z += a.z*s; acc.w += a.w*s;
}

// ---------------- counting sort of edges by idx_i ----------------

__global__ void zero_counts_kernel(int* __restrict__ counts) {
    int i = blockIdx.x * 256 + threadIdx.x;
    if (i < N_ATOMS) counts[i] = 0;
}

__global__ void hist_kernel(const int* __restrict__ idx_i, int* __restrict__ counts) {
    int e = blockIdx.x * 256 + threadIdx.x;
    if (e < N_EDGES) atomicAdd(&counts[idx_i[e]], 1);
}

// single-block exclusive scan over 20000 counts -> offsets[20001], cursor copy
__global__ __launch_bounds__(1024) void scan_kernel(const int* __restrict__ counts,
                                                    int* __restrict__ offsets,
                                                    int* __restrict__ cursor) {
    __shared__ int ls[1024];
    const int CH = 20;                     // 1024*20 = 20480 >= 20000
    int t = threadIdx.x;
    int beg = t * CH;
    int end = beg + CH; if (end > N_ATOMS) end = N_ATOMS;
    int s = 0;
    for (int i = beg; i < end && i < N_ATOMS; ++i) s += counts[i];
    ls[t] = s;
    __syncthreads();
    // Hillis-Steele inclusive scan
    for (int off = 1; off < 1024; off <<= 1) {
        int v = (t >= off) ? ls[t - off] : 0;
        __syncthreads();
        ls[t] += v;
        __syncthreads();
    }
    int excl = ls[t] - s;
    int run = excl;
    for (int i = beg; i < end && i < N_ATOMS; ++i) {
        offsets[i] = run;
        cursor[i]  = run;
        run += counts[i];
    }
    if (t == 1023) offsets[N_ATOMS] = ls[1023];
}

__global__ void scatter_kernel(const int* __restrict__ idx_i,
                               int* __restrict__ cursor, int* __restrict__ perm) {
    int e = blockIdx.x * 256 + threadIdx.x;
    if (e < N_EDGES) {
        int pos = atomicAdd(&cursor[idx_i[e]], 1);
        perm[pos] = e;
    }
}

// ---------------- per-atom MLP: two tiled fp32 GEMMs ----------------
// C[M x Nout] = actfn(A[M x 128] @ W[128 x Nout] + bias)
__global__ __launch_bounds__(256) void gemm_bias_act(const float* __restrict__ A,
                                                     const float* __restrict__ W,
                                                     const float* __restrict__ bias,
                                                     float* __restrict__ C,
                                                     int M, int Nout, int act) {
    __shared__ float As[64 * 132];    // 64 rows x 128 cols, pad stride 132
    __shared__ float Bs[128 * 68];    // 128 rows x 64 cols, pad stride 68
    int tid  = threadIdx.x;
    int row0 = blockIdx.x * 64;
    int col0 = blockIdx.y * 64;

    // stage A tile (guard rows)
    for (int t = tid; t < 64 * 32; t += 256) {
        int m = t >> 5, k4 = (t & 31) * 4;
        float4 v = make_float4(0.f, 0.f, 0.f, 0.f);
        int gr = row0 + m;
        if (gr < M) v = ld4(A + (size_t)gr * 128 + k4);
        st4(As + m * 132 + k4, v);
    }
    // stage W tile (always in-bounds: Nout % 64 == 0, K = 128)
    for (int t = tid; t < 128 * 16; t += 256) {
        int k = t >> 4, n4 = (t & 15) * 4;
        st4(Bs + k * 68 + n4, ld4(W + (size_t)k * Nout + col0 + n4));
    }
    __syncthreads();

    int tx = tid & 15, ty = tid >> 4;
    int cc = col0 + tx * 4;
    float4 bv = ld4(bias + cc);
    float4 acc[4];
    acc[0] = bv; acc[1] = bv; acc[2] = bv; acc[3] = bv;

    const float* Ap = As + (ty * 4) * 132;
    for (int k = 0; k < 128; k += 4) {
        float4 a0 = ld4(Ap + 0 * 132 + k);
        float4 a1 = ld4(Ap + 1 * 132 + k);
        float4 a2 = ld4(Ap + 2 * 132 + k);
        float4 a3 = ld4(Ap + 3 * 132 + k);
        float4 b0 = ld4(Bs + (k + 0) * 68 + tx * 4);
        float4 b1 = ld4(Bs + (k + 1) * 68 + tx * 4);
        float4 b2 = ld4(Bs + (k + 2) * 68 + tx * 4);
        float4 b3 = ld4(Bs + (k + 3) * 68 + tx * 4);
        fma4s(acc[0], b0, a0.x); fma4s(acc[0], b1, a0.y); fma4s(acc[0], b2, a0.z); fma4s(acc[0], b3, a0.w);
        fma4s(acc[1], b0, a1.x); fma4s(acc[1], b1, a1.y); fma4s(acc[1], b2, a1.z); fma4s(acc[1], b3, a1.w);
        fma4s(acc[2], b0, a2.x); fma4s(acc[2], b1, a2.y); fma4s(acc[2], b2, a2.z); fma4s(acc[2], b3, a2.w);
        fma4s(acc[3], b0, a3.x); fma4s(acc[3], b1, a3.y); fma4s(acc[3], b2, a3.z); fma4s(acc[3], b3, a3.w);
    }

    #pragma unroll
    for (int mi = 0; mi < 4; ++mi) {
        float4 v = acc[mi];
        if (act) {
            v.x = v.x / (1.0f + __expf(-v.x));
            v.y = v.y / (1.0f + __expf(-v.y));
            v.z = v.z / (1.0f + __expf(-v.z));
            v.w = v.w / (1.0f + __expf(-v.w));
        }
        int gr = row0 + ty * 4 + mi;
        if (gr < M) st4(C + (size_t)gr * Nout + cc, v);
    }
}

// ---------------- fused edge gather + segment accumulate ----------------
// 32 lanes per atom, 4 features per lane. out = q+dq, mu+dmu (plain stores).
__global__ __launch_bounds__(256) void gather_kernel(const float* __restrict__ q,
                                                     const float* __restrict__ mu,
                                                     const float* __restrict__ Wij,
                                                     const float* __restrict__ dir_ij,
                                                     const int* __restrict__ idx_j,
                                                     const int* __restrict__ offsets,
                                                     const int* __restrict__ perm,
                                                     const float* __restrict__ x,
                                                     float* __restrict__ out_q,
                                                     float* __restrict__ out_mu) {
    int l4 = (threadIdx.x & 31) * 4;                  // feature offset (0..124)
    int a  = blockIdx.x * 8 + (threadIdx.x >> 5);     // 2500 * 8 == 20000 exact

    float4 aq = ld4(q + (size_t)a * FDIM + l4);
    const float* mb = mu + (size_t)a * TFDIM;
    float4 am0 = ld4(mb + l4);
    float4 am1 = ld4(mb + 128 + l4);
    float4 am2 = ld4(mb + 256 + l4);

    int s = offsets[a];
    int t = offsets[a + 1];
    for (int k = s; k < t; ++k) {
        int e = perm[k];
        int j = idx_j[e];
        const float* w  = Wij + (size_t)e * TFDIM;
        const float* xj = x   + (size_t)j * TFDIM;
        const float* mj = mu  + (size_t)j * TFDIM;
        float4 w0 = ld4(w + l4),        x0 = ld4(xj + l4);
        float4 w1 = ld4(w + 128 + l4),  x1 = ld4(xj + 128 + l4);
        float4 w2 = ld4(w + 256 + l4),  x2 = ld4(xj + 256 + l4);
        float dx = dir_ij[3 * (size_t)e + 0];
        float dy = dir_ij[3 * (size_t)e + 1];
        float dz = dir_ij[3 * (size_t)e + 2];
        float4 m0 = ld4(mj + l4);
        float4 m1 = ld4(mj + 128 + l4);
        float4 m2 = ld4(mj + 256 + l4);

        fma4(aq, w0, x0);                 // dq
        float4 dR = mul4(w1, x1);         // dmuR
        float4 dM = mul4(w2, x2);         // dmumu
        fma4s(am0, dR, dx); fma4(am0, dM, m0);
        fma4s(am1, dR, dy); fma4(am1, dM, m1);
        fma4s(am2, dR, dz); fma4(am2, dM, m2);
    }

    st4(out_q + (size_t)a * FDIM + l4, aq);
    float* ob = out_mu + (size_t)a * TFDIM;
    st4(ob + l4,        am0);
    st4(ob + 128 + l4,  am1);
    st4(ob + 256 + l4,  am2);
}

extern "C" void kernel_launch(void* const* d_in, const int* in_sizes, int n_in,
                              void* d_out, int out_size, void* d_ws, size_t ws_size,
                              hipStream_t stream) {
    const float* q      = (const float*)d_in[0];   // [20000,1,128]
    const float* mu     = (const float*)d_in[1];   // [20000,3,128]
    const float* Wij    = (const float*)d_in[2];   // [500000,1,384]
    const float* dir_ij = (const float*)d_in[3];   // [500000,3]
    const int*   idx_i  = (const int*)d_in[4];     // [500000]
    const int*   idx_j  = (const int*)d_in[5];     // [500000]
    // d_in[6] = n_atoms scalar (20000), compile-time constant here
    const float* W1     = (const float*)d_in[7];   // [128,128]
    const float* b1     = (const float*)d_in[8];   // [128]
    const float* W2     = (const float*)d_in[9];   // [128,384]
    const float* b2     = (const float*)d_in[10];  // [384]

    float* out_q  = (float*)d_out;                 // 20000*128
    float* out_mu = out_q + (size_t)N_ATOMS * FDIM;// 20000*384

    // workspace layout
    float* xw     = (float*)d_ws;                       // 20000*384 floats
    float* hw     = xw + (size_t)N_ATOMS * TFDIM;       // 20000*128 floats
    int*   counts = (int*)(hw + (size_t)N_ATOMS * FDIM);
    int*   offs   = counts + N_ATOMS;                   // N_ATOMS+1
    int*   cursor = offs + (N_ATOMS + 1);
    int*   perm   = cursor + N_ATOMS;                   // N_EDGES

    const int eblocks = (N_EDGES + 255) / 256;

    zero_counts_kernel<<<(N_ATOMS + 255) / 256, 256, 0, stream>>>(counts);
    hist_kernel<<<eblocks, 256, 0, stream>>>(idx_i, counts);
    scan_kernel<<<1, 1024, 0, stream>>>(counts, offs, cursor);
    scatter_kernel<<<eblocks, 256, 0, stream>>>(idx_i, cursor, perm);

    gemm_bias_act<<<dim3(313, 2), 256, 0, stream>>>(q,  W1, b1, hw, N_ATOMS, 128, 1);
    gemm_bias_act<<<dim3(313, 6), 256, 0, stream>>>(hw, W2, b2, xw, N_ATOMS, 384, 0);

    gather_kernel<<<2500, 256, 0, stream>>>(q, mu, Wij, dir_ij, idx_j, offs, perm,
                                            xw, out_q, out_mu);
}

// Round 2
// 1311.812 us; speedup vs baseline: 1.0142x; 1.0142x over previous
//
#include <hip/hip_runtime.h>
#include <hip/hip_bf16.h>

#define N_ATOMS 20000
#define N_EDGES 500000
#define FDIM    128
#define TFDIM   384

__device__ inline float4 ld4(const float* p) { return *(const float4*)p; }
__device__ inline void st4(float* p, float4 v) { *(float4*)p = v; }
__device__ inline float4 mul4(float4 a, float4 b) {
    return make_float4(a.x*b.x, a.y*b.y, a.z*b.z, a.w*b.w);
}
__device__ inline void fma4(float4& acc, float4 a, float4 b) {
    acc.x += a.x*b.x; acc.y += a.y*b.y; acc.z += a.z*b.z; acc.w += a.w*b.w;
}
__device__ inline void fma4s(float4& acc, float4 a, float s) {
    acc.x += a.x*s; acc.y += a.y*s; acc.z += a.z*s; acc.w += a.w*s;
}

// ---------------- counting sort of edges by idx_i ----------------

__global__ void zero_counts_kernel(int* __restrict__ counts) {
    int i = blockIdx.x * 256 + threadIdx.x;
    if (i < N_ATOMS) counts[i] = 0;
}

__global__ void hist_kernel(const int* __restrict__ idx_i, int* __restrict__ counts) {
    int e = blockIdx.x * 256 + threadIdx.x;
    if (e < N_EDGES) atomicAdd(&counts[idx_i[e]], 1);
}

// single-block exclusive scan over 20000 counts -> offsets[20001], cursor copy
__global__ __launch_bounds__(1024) void scan_kernel(const int* __restrict__ counts,
                                                    int* __restrict__ offsets,
                                                    int* __restrict__ cursor) {
    __shared__ int ls[1024];
    const int CH = 20;                     // 1024*20 = 20480 >= 20000
    int t = threadIdx.x;
    int beg = t * CH;
    int end = beg + CH; if (end > N_ATOMS) end = N_ATOMS;
    int s = 0;
    for (int i = beg; i < end && i < N_ATOMS; ++i) s += counts[i];
    ls[t] = s;
    __syncthreads();
    for (int off = 1; off < 1024; off <<= 1) {
        int v = (t >= off) ? ls[t - off] : 0;
        __syncthreads();
        ls[t] += v;
        __syncthreads();
    }
    int excl = ls[t] - s;
    int run = excl;
    for (int i = beg; i < end && i < N_ATOMS; ++i) {
        offsets[i] = run;
        cursor[i]  = run;
        run += counts[i];
    }
    if (t == 1023) offsets[N_ATOMS] = ls[1023];
}

// scatter edge ids; also resolve idx_j so gather needs no dependent random load
__global__ void scatter_kernel(const int* __restrict__ idx_i,
                               const int* __restrict__ idx_j,
                               int* __restrict__ cursor, int2* __restrict__ perm2) {
    int e = blockIdx.x * 256 + threadIdx.x;
    if (e < N_EDGES) {
        int pos = atomicAdd(&cursor[idx_i[e]], 1);
        perm2[pos] = make_int2(e, idx_j[e]);
    }
}

// ---------------- per-atom MLP: two tiled fp32 GEMMs ----------------
__global__ __launch_bounds__(256) void gemm_bias_act(const float* __restrict__ A,
                                                     const float* __restrict__ W,
                                                     const float* __restrict__ bias,
                                                     float* __restrict__ C,
                                                     int M, int Nout, int act) {
    __shared__ float As[64 * 132];
    __shared__ float Bs[128 * 68];
    int tid  = threadIdx.x;
    int row0 = blockIdx.x * 64;
    int col0 = blockIdx.y * 64;

    for (int t = tid; t < 64 * 32; t += 256) {
        int m = t >> 5, k4 = (t & 31) * 4;
        float4 v = make_float4(0.f, 0.f, 0.f, 0.f);
        int gr = row0 + m;
        if (gr < M) v = ld4(A + (size_t)gr * 128 + k4);
        st4(As + m * 132 + k4, v);
    }
    for (int t = tid; t < 128 * 16; t += 256) {
        int k = t >> 4, n4 = (t & 15) * 4;
        st4(Bs + k * 68 + n4, ld4(W + (size_t)k * Nout + col0 + n4));
    }
    __syncthreads();

    int tx = tid & 15, ty = tid >> 4;
    int cc = col0 + tx * 4;
    float4 bv = ld4(bias + cc);
    float4 acc[4];
    acc[0] = bv; acc[1] = bv; acc[2] = bv; acc[3] = bv;

    const float* Ap = As + (ty * 4) * 132;
    for (int k = 0; k < 128; k += 4) {
        float4 a0 = ld4(Ap + 0 * 132 + k);
        float4 a1 = ld4(Ap + 1 * 132 + k);
        float4 a2 = ld4(Ap + 2 * 132 + k);
        float4 a3 = ld4(Ap + 3 * 132 + k);
        float4 b0 = ld4(Bs + (k + 0) * 68 + tx * 4);
        float4 b1 = ld4(Bs + (k + 1) * 68 + tx * 4);
        float4 b2 = ld4(Bs + (k + 2) * 68 + tx * 4);
        float4 b3 = ld4(Bs + (k + 3) * 68 + tx * 4);
        fma4s(acc[0], b0, a0.x); fma4s(acc[0], b1, a0.y); fma4s(acc[0], b2, a0.z); fma4s(acc[0], b3, a0.w);
        fma4s(acc[1], b0, a1.x); fma4s(acc[1], b1, a1.y); fma4s(acc[1], b2, a1.z); fma4s(acc[1], b3, a1.w);
        fma4s(acc[2], b0, a2.x); fma4s(acc[2], b1, a2.y); fma4s(acc[2], b2, a2.z); fma4s(acc[2], b3, a2.w);
        fma4s(acc[3], b0, a3.x); fma4s(acc[3], b1, a3.y); fma4s(acc[3], b2, a3.z); fma4s(acc[3], b3, a3.w);
    }

    #pragma unroll
    for (int mi = 0; mi < 4; ++mi) {
        float4 v = acc[mi];
        if (act) {
            v.x = v.x / (1.0f + __expf(-v.x));
            v.y = v.y / (1.0f + __expf(-v.y));
            v.z = v.z / (1.0f + __expf(-v.z));
            v.w = v.w / (1.0f + __expf(-v.w));
        }
        int gr = row0 + ty * 4 + mi;
        if (gr < M) st4(C + (size_t)gr * Nout + cc, v);
    }
}

// ---------------- fused edge gather + segment accumulate ----------------
// One wave64 per atom. Lanes 0-31 process even edges, 32-63 odd edges.
// Each half-lane owns 4 features. Partials combined via shfl_xor(32).
__global__ __launch_bounds__(256) void gather_kernel(const float* __restrict__ q,
                                                     const float* __restrict__ mu,
                                                     const float* __restrict__ Wij,
                                                     const float* __restrict__ dir_ij,
                                                     const int* __restrict__ offsets,
                                                     const int2* __restrict__ perm2,
                                                     const float* __restrict__ x,
                                                     float* __restrict__ out_q,
                                                     float* __restrict__ out_mu) {
    int lane = threadIdx.x & 63;
    int wid  = threadIdx.x >> 6;
    int a    = blockIdx.x * 4 + wid;          // 5000 * 4 == 20000 exact
    int half = lane >> 5;                     // 0 or 1
    int l4   = (lane & 31) * 4;               // feature offset

    float4 aq  = make_float4(0.f, 0.f, 0.f, 0.f);
    float4 am0 = aq, am1 = aq, am2 = aq;

    int s = offsets[a];
    int t = offsets[a + 1];
    int k = s + half;

    int e = 0, j = 0;
    if (k < t) { int2 p = perm2[k]; e = p.x; j = p.y; }

    for (; k < t; k += 2) {
        // prefetch next pair before the heavy loads
        int kn = k + 2;
        int2 pn = (kn < t) ? perm2[kn] : make_int2(0, 0);

        const float* w  = Wij + (size_t)e * TFDIM;
        const float* xj = x   + (size_t)j * TFDIM;
        const float* mj = mu  + (size_t)j * TFDIM;
        float dx = dir_ij[3 * (size_t)e + 0];
        float dy = dir_ij[3 * (size_t)e + 1];
        float dz = dir_ij[3 * (size_t)e + 2];
        float4 w0 = ld4(w + l4),       x0 = ld4(xj + l4);
        float4 w1 = ld4(w + 128 + l4), x1 = ld4(xj + 128 + l4);
        float4 w2 = ld4(w + 256 + l4), x2 = ld4(xj + 256 + l4);
        float4 m0 = ld4(mj + l4);
        float4 m1 = ld4(mj + 128 + l4);
        float4 m2 = ld4(mj + 256 + l4);

        fma4(aq, w0, x0);
        float4 dR = mul4(w1, x1);
        float4 dM = mul4(w2, x2);
        fma4s(am0, dR, dx); fma4(am0, dM, m0);
        fma4s(am1, dR, dy); fma4(am1, dM, m1);
        fma4s(am2, dR, dz); fma4(am2, dM, m2);

        e = pn.x; j = pn.y;
    }

    // combine the two half-wave partials (lane ^ 32)
    aq.x  += __shfl_xor(aq.x, 32);  aq.y  += __shfl_xor(aq.y, 32);
    aq.z  += __shfl_xor(aq.z, 32);  aq.w  += __shfl_xor(aq.w, 32);
    am0.x += __shfl_xor(am0.x, 32); am0.y += __shfl_xor(am0.y, 32);
    am0.z += __shfl_xor(am0.z, 32); am0.w += __shfl_xor(am0.w, 32);
    am1.x += __shfl_xor(am1.x, 32); am1.y += __shfl_xor(am1.y, 32);
    am1.z += __shfl_xor(am1.z, 32); am1.w += __shfl_xor(am1.w, 32);
    am2.x += __shfl_xor(am2.x, 32); am2.y += __shfl_xor(am2.y, 32);
    am2.z += __shfl_xor(am2.z, 32); am2.w += __shfl_xor(am2.w, 32);

    if (half == 0) {
        float4 qv = ld4(q + (size_t)a * FDIM + l4);
        st4(out_q + (size_t)a * FDIM + l4,
            make_float4(qv.x + aq.x, qv.y + aq.y, qv.z + aq.z, qv.w + aq.w));
        const float* mb = mu + (size_t)a * TFDIM;
        float* ob = out_mu + (size_t)a * TFDIM;
        float4 mv0 = ld4(mb + l4);
        float4 mv1 = ld4(mb + 128 + l4);
        float4 mv2 = ld4(mb + 256 + l4);
        st4(ob + l4,       make_float4(mv0.x + am0.x, mv0.y + am0.y, mv0.z + am0.z, mv0.w + am0.w));
        st4(ob + 128 + l4, make_float4(mv1.x + am1.x, mv1.y + am1.y, mv1.z + am1.z, mv1.w + am1.w));
        st4(ob + 256 + l4, make_float4(mv2.x + am2.x, mv2.y + am2.y, mv2.z + am2.z, mv2.w + am2.w));
    }
}

extern "C" void kernel_launch(void* const* d_in, const int* in_sizes, int n_in,
                              void* d_out, int out_size, void* d_ws, size_t ws_size,
                              hipStream_t stream) {
    const float* q      = (const float*)d_in[0];
    const float* mu     = (const float*)d_in[1];
    const float* Wij    = (const float*)d_in[2];
    const float* dir_ij = (const float*)d_in[3];
    const int*   idx_i  = (const int*)d_in[4];
    const int*   idx_j  = (const int*)d_in[5];
    const float* W1     = (const float*)d_in[7];
    const float* b1     = (const float*)d_in[8];
    const float* W2     = (const float*)d_in[9];
    const float* b2     = (const float*)d_in[10];

    float* out_q  = (float*)d_out;
    float* out_mu = out_q + (size_t)N_ATOMS * FDIM;

    // workspace layout (keep perm2 8-byte aligned)
    float* xw     = (float*)d_ws;                        // 20000*384
    float* hw     = xw + (size_t)N_ATOMS * TFDIM;        // 20000*128
    int*   counts = (int*)(hw + (size_t)N_ATOMS * FDIM); // 20000
    int*   offs   = counts + N_ATOMS;                    // 20001
    int*   cursor = offs + (N_ATOMS + 1);                // 20000
    int*   pad    = cursor + N_ATOMS;                    // 1 pad -> 8B align
    int2*  perm2  = (int2*)(pad + 1);                    // 500000 int2

    const int eblocks = (N_EDGES + 255) / 256;

    zero_counts_kernel<<<(N_ATOMS + 255) / 256, 256, 0, stream>>>(counts);
    hist_kernel<<<eblocks, 256, 0, stream>>>(idx_i, counts);
    scan_kernel<<<1, 1024, 0, stream>>>(counts, offs, cursor);
    scatter_kernel<<<eblocks, 256, 0, stream>>>(idx_i, idx_j, cursor, perm2);

    gemm_bias_act<<<dim3(313, 2), 256, 0, stream>>>(q,  W1, b1, hw, N_ATOMS, 128, 1);
    gemm_bias_act<<<dim3(313, 6), 256, 0, stream>>>(hw, W2, b2, xw, N_ATOMS, 384, 0);

    gather_kernel<<<5000, 256, 0, stream>>>(q, mu, Wij, dir_ij, offs, perm2,
                                            xw, out_q, out_mu);
}